// Round 3
// baseline (5254.147 us; speedup 1.0000x reference)
//
#include <hip/hip_runtime.h>

#define N_NODES 150018
#define DIMS 64
#define NELEM (N_NODES * DIMS)            // 9,601,152 floats
#define NBKT ((N_NODES + 63) >> 6)        // 2345 buckets of 64 rows
#define SC_BLOCKS 512
#define SC_THREADS 256

// ---- bucket histogram: LDS-privatized, coalesced global merge -----------
__global__ void hist_bucket_k(const int* __restrict__ rows, int* __restrict__ counts,
                              int n, int chunk) {
    __shared__ int h[NBKT];
    for (int i = threadIdx.x; i < NBKT; i += blockDim.x) h[i] = 0;
    __syncthreads();
    int beg = blockIdx.x * chunk;
    int end = min(n, beg + chunk);
    for (int e = beg + threadIdx.x; e < end; e += blockDim.x)
        atomicAdd(&h[rows[e] >> 6], 1);
    __syncthreads();
    for (int i = threadIdx.x; i < NBKT; i += blockDim.x)
        if (h[i]) atomicAdd(&counts[i], h[i]);
}

// ---- exclusive scan of 2345 bucket counts (single block) ----------------
__global__ void scan_bucket_k(const int* __restrict__ counts, int* __restrict__ offs,
                              int* __restrict__ cursor, int n_edges) {
    __shared__ int s[1024];
    __shared__ int carry;
    if (threadIdx.x == 0) carry = 0;
    __syncthreads();
    for (int t = 0; t < NBKT; t += 1024) {
        int i = t + threadIdx.x;
        int v = (i < NBKT) ? counts[i] : 0;
        s[threadIdx.x] = v;
        __syncthreads();
        for (int off = 1; off < 1024; off <<= 1) {
            int tv = (threadIdx.x >= off) ? s[threadIdx.x - off] : 0;
            __syncthreads();
            s[threadIdx.x] += tv;
            __syncthreads();
        }
        if (i < NBKT) {
            int ex = carry + s[threadIdx.x] - v;   // exclusive prefix
            offs[i] = ex;
            cursor[i] = ex;
        }
        __syncthreads();
        if (threadIdx.x == 1023) carry += s[1023];
        __syncthreads();
    }
    if (threadIdx.x == 0) offs[NBKT] = n_edges;
}

// ---- two-pass per-block bucket scatter ----------------------------------
// edges[pos] = (col | slot<<18, val_bits); pos contiguous per (block,bucket)
__global__ void scatter_bucket_k(const int* __restrict__ rows, const int* __restrict__ cols,
                                 const float* __restrict__ vals, int* __restrict__ cursor,
                                 int2* __restrict__ edges, int n, int chunk) {
    __shared__ int cnt[NBKT];
    __shared__ int base[NBKT];
    for (int i = threadIdx.x; i < NBKT; i += blockDim.x) cnt[i] = 0;
    __syncthreads();
    int beg = blockIdx.x * chunk;
    int end = min(n, beg + chunk);
    for (int e = beg + threadIdx.x; e < end; e += blockDim.x)
        atomicAdd(&cnt[rows[e] >> 6], 1);
    __syncthreads();
    for (int i = threadIdx.x; i < NBKT; i += blockDim.x) {
        int c = cnt[i];
        base[i] = c ? atomicAdd(&cursor[i], c) : 0;
        cnt[i] = 0;   // reuse as running rank
    }
    __syncthreads();
    for (int e = beg + threadIdx.x; e < end; e += blockDim.x) {
        int r = rows[e];
        int b = r >> 6;
        int pos = base[b] + atomicAdd(&cnt[b], 1);
        edges[pos] = make_int2(cols[e] | ((r & 63) << 18), __float_as_int(vals[e]));
    }
}

// ---- bucket SpMM: block per 64-row bucket, LDS f32 accumulator ----------
// res = A_bucket * x ; buf_out = res (if write_buf) ; acc_out = (acc_in+res)*scale
__global__ __launch_bounds__(256) void spmm_bucket_k(const float* __restrict__ x,
                           const int2* __restrict__ edges,
                           const int* __restrict__ offs,
                           const float* __restrict__ acc_in,
                           float* __restrict__ buf_out,
                           float* __restrict__ acc_out,
                           float scale, int write_buf) {
    __shared__ float acc[64 * DIMS];   // 16 KB
    const int b    = blockIdx.x;
    const int lane = threadIdx.x & 63;
    const int wv   = threadIdx.x >> 6;
    for (int i = threadIdx.x; i < 64 * DIMS; i += 256) acc[i] = 0.f;
    __syncthreads();
    const int beg = offs[b], end = offs[b + 1];
    for (int e = beg + wv; e < end; e += 4) {
        int2 ed = edges[e];                     // wave-uniform load
        int   c    = ed.x & 0x3FFFF;
        int   slot = ed.x >> 18;
        float v    = __int_as_float(ed.y);
        atomicAdd(&acc[(slot << 6) + lane], v * x[(c << 6) + lane]);
    }
    __syncthreads();
    #pragma unroll
    for (int j = 0; j < 16; ++j) {
        int slot = wv + (j << 2);
        int g = (b << 6) + slot;
        if (g < N_NODES) {
            int o = (g << 6) + lane;
            float r = acc[(slot << 6) + lane];
            if (write_buf) buf_out[o] = r;
            acc_out[o] = (acc_in[o] + r) * scale;
        }
    }
}

// ---- launch -------------------------------------------------------------
extern "C" void kernel_launch(void* const* d_in, const int* in_sizes, int n_in,
                              void* d_out, int out_size, void* d_ws, size_t ws_size,
                              hipStream_t stream) {
    const float* emb  = (const float*)d_in[0];
    const float* vals = (const float*)d_in[1];
    const int*   rows = (const int*)d_in[2];
    const int*   cols = (const int*)d_in[3];
    float*       out  = (float*)d_out;
    const int n_edges = in_sizes[1];

    char* w = (char*)d_ws;
    float* bufA  = (float*)w;  w += (size_t)NELEM * 4;
    float* bufB  = (float*)w;  w += (size_t)NELEM * 4;
    int2*  edges = (int2*)w;   w += (size_t)n_edges * 8;
    int* counts  = (int*)w;    w += (size_t)NBKT * 4;
    int* offs    = (int*)w;    w += (size_t)(NBKT + 1) * 4;
    int* cursor  = (int*)w;

    const int chunk = (n_edges + SC_BLOCKS - 1) / SC_BLOCKS;

    hipMemsetAsync(counts, 0, (size_t)NBKT * 4, stream);
    hist_bucket_k<<<SC_BLOCKS, SC_THREADS, 0, stream>>>(rows, counts, n_edges, chunk);
    scan_bucket_k<<<1, 1024, 0, stream>>>(counts, offs, cursor, n_edges);
    scatter_bucket_k<<<SC_BLOCKS, SC_THREADS, 0, stream>>>(rows, cols, vals, cursor,
                                                           edges, n_edges, chunk);

    // L1: x=emb -> r1 ; bufA=r1 ; out = emb + r1
    spmm_bucket_k<<<NBKT, 256, 0, stream>>>(emb, edges, offs, emb, bufA, out, 1.0f, 1);
    // L2: x=bufA -> r2 ; bufB=r2 ; out += r2
    spmm_bucket_k<<<NBKT, 256, 0, stream>>>(bufA, edges, offs, out, bufB, out, 1.0f, 1);
    // L3: x=bufB -> r3 ; out = (out + r3) * 0.25
    spmm_bucket_k<<<NBKT, 256, 0, stream>>>(bufB, edges, offs, out, nullptr, out, 0.25f, 0);
}

// Round 4
// 736.874 us; speedup vs baseline: 7.1303x; 7.1303x over previous
//
#include <hip/hip_runtime.h>

#define N_NODES 150018
#define DIMS 64
#define NELEM (N_NODES * DIMS)            // 9,601,152 floats
#define NBKT ((N_NODES + 63) >> 6)        // 2345 buckets of 64 rows
#define NROWS_PAD (NBKT << 6)             // 150080
#define SC_BLOCKS 512
#define SC_THREADS 256

// ---- bucket histogram: LDS-privatized, coalesced global merge -----------
__global__ void hist_bucket_k(const int* __restrict__ rows, int* __restrict__ counts,
                              int n, int chunk) {
    __shared__ int h[NBKT];
    for (int i = threadIdx.x; i < NBKT; i += blockDim.x) h[i] = 0;
    __syncthreads();
    int beg = blockIdx.x * chunk;
    int end = min(n, beg + chunk);
    for (int e = beg + threadIdx.x; e < end; e += blockDim.x)
        atomicAdd(&h[rows[e] >> 6], 1);
    __syncthreads();
    for (int i = threadIdx.x; i < NBKT; i += blockDim.x)
        if (h[i]) atomicAdd(&counts[i], h[i]);
}

// ---- exclusive scan of bucket counts (single block) ---------------------
__global__ void scan_bucket_k(const int* __restrict__ counts, int* __restrict__ offs,
                              int* __restrict__ cursor, int n_edges) {
    __shared__ int s[1024];
    __shared__ int carry;
    if (threadIdx.x == 0) carry = 0;
    __syncthreads();
    for (int t = 0; t < NBKT; t += 1024) {
        int i = t + threadIdx.x;
        int v = (i < NBKT) ? counts[i] : 0;
        s[threadIdx.x] = v;
        __syncthreads();
        for (int off = 1; off < 1024; off <<= 1) {
            int tv = (threadIdx.x >= off) ? s[threadIdx.x - off] : 0;
            __syncthreads();
            s[threadIdx.x] += tv;
            __syncthreads();
        }
        if (i < NBKT) {
            int ex = carry + s[threadIdx.x] - v;
            offs[i] = ex;
            cursor[i] = ex;
        }
        __syncthreads();
        if (threadIdx.x == 1023) carry += s[1023];
        __syncthreads();
    }
    if (threadIdx.x == 0) offs[NBKT] = n_edges;
}

// ---- two-pass per-block bucket scatter (contiguous runs per block) ------
// edges1[pos] = (col | slot<<18, val_bits)
__global__ void scatter_bucket_k(const int* __restrict__ rows, const int* __restrict__ cols,
                                 const float* __restrict__ vals, int* __restrict__ cursor,
                                 int2* __restrict__ edges1, int n, int chunk) {
    __shared__ int cnt[NBKT];
    __shared__ int base[NBKT];
    for (int i = threadIdx.x; i < NBKT; i += blockDim.x) cnt[i] = 0;
    __syncthreads();
    int beg = blockIdx.x * chunk;
    int end = min(n, beg + chunk);
    for (int e = beg + threadIdx.x; e < end; e += blockDim.x)
        atomicAdd(&cnt[rows[e] >> 6], 1);
    __syncthreads();
    for (int i = threadIdx.x; i < NBKT; i += blockDim.x) {
        int c = cnt[i];
        base[i] = c ? atomicAdd(&cursor[i], c) : 0;
        cnt[i] = 0;   // reuse as running rank
    }
    __syncthreads();
    for (int e = beg + threadIdx.x; e < end; e += blockDim.x) {
        int r = rows[e];
        int b = r >> 6;
        int pos = base[b] + atomicAdd(&cnt[b], 1);
        edges1[pos] = make_int2(cols[e] | ((r & 63) << 18), __float_as_int(vals[e]));
    }
}

// ---- per-bucket 64-bin counting sort -> row-sorted edges + row offsets --
__global__ __launch_bounds__(256) void sort_bucket_k(const int2* __restrict__ e1,
                                 const int* __restrict__ bkt_offs,
                                 int2* __restrict__ e2,
                                 int* __restrict__ row_offs) {
    __shared__ int cnt[64];
    __shared__ int pref[64];
    int b = blockIdx.x;
    int beg = bkt_offs[b], end = bkt_offs[b + 1];
    if (threadIdx.x < 64) cnt[threadIdx.x] = 0;
    __syncthreads();
    for (int e = beg + threadIdx.x; e < end; e += 256)
        atomicAdd(&cnt[e1[e].x >> 18], 1);
    __syncthreads();
    if (threadIdx.x == 0) {
        int s = 0;
        for (int i = 0; i < 64; ++i) { pref[i] = s; s += cnt[i]; }
    }
    __syncthreads();
    if (threadIdx.x < 64) {
        row_offs[(b << 6) + threadIdx.x] = beg + pref[threadIdx.x];
        cnt[threadIdx.x] = 0;   // reuse as rank
    }
    __syncthreads();
    for (int e = beg + threadIdx.x; e < end; e += 256) {
        int2 ed = e1[e];
        int slot = ed.x >> 18;
        int pos = beg + pref[slot] + atomicAdd(&cnt[slot], 1);
        e2[pos] = make_int2(ed.x & 0x3FFFF, ed.y);
    }
}

// ---- SpMM: wave per row, 4 edges in flight via 16-lane float4 groups ----
// r = A[row]·x ; buf_out=r (if non-null) ; acc_out = (acc_in + r)*scale
__global__ __launch_bounds__(256) void spmm_row_k(const float4* __restrict__ x4,
                          const int2* __restrict__ edges,
                          const int* __restrict__ offs,
                          const float4* __restrict__ acc_in,
                          float4* __restrict__ buf_out,
                          float4* __restrict__ acc_out,
                          float scale, int n_rows) {
    int row = (blockIdx.x * blockDim.x + threadIdx.x) >> 6;
    if (row >= n_rows) return;
    int lane = threadIdx.x & 63;
    int g = lane >> 4;          // edge subgroup 0..3
    int q = lane & 15;          // float4 index within row
    int beg = offs[row], end = offs[row + 1];
    float4 a = make_float4(0.f, 0.f, 0.f, 0.f);
    for (int e = beg; e < end; e += 4) {
        int idx = e + g;
        float v = 0.f;
        int c = 0;
        if (idx < end) {
            int2 ed = edges[idx];
            c = ed.x;
            v = __int_as_float(ed.y);
        }
        float4 xv = x4[(c << 4) + q];
        a.x = fmaf(v, xv.x, a.x);
        a.y = fmaf(v, xv.y, a.y);
        a.z = fmaf(v, xv.z, a.z);
        a.w = fmaf(v, xv.w, a.w);
    }
    // reduce across the 4 subgroups (lane bits 4 and 5)
    #pragma unroll
    for (int m = 16; m <= 32; m <<= 1) {
        a.x += __shfl_xor(a.x, m, 64);
        a.y += __shfl_xor(a.y, m, 64);
        a.z += __shfl_xor(a.z, m, 64);
        a.w += __shfl_xor(a.w, m, 64);
    }
    int o = (row << 4) + q;
    if (g == 0 && buf_out) buf_out[o] = a;
    if (g == 1) {
        float4 ai = acc_in[o];
        ai.x = (ai.x + a.x) * scale;
        ai.y = (ai.y + a.y) * scale;
        ai.z = (ai.z + a.z) * scale;
        ai.w = (ai.w + a.w) * scale;
        acc_out[o] = ai;
    }
}

// ---- launch -------------------------------------------------------------
extern "C" void kernel_launch(void* const* d_in, const int* in_sizes, int n_in,
                              void* d_out, int out_size, void* d_ws, size_t ws_size,
                              hipStream_t stream) {
    const float* emb  = (const float*)d_in[0];
    const float* vals = (const float*)d_in[1];
    const int*   rows = (const int*)d_in[2];
    const int*   cols = (const int*)d_in[3];
    float*       out  = (float*)d_out;
    const int n_edges = in_sizes[1];

    // workspace: region1 is edges1 during build, bufA during SpMMs
    char* w = (char*)d_ws;
    int2*  edges1 = (int2*)w;
    float* bufA   = (float*)w;   w += (size_t)NELEM * 4;     // >= n_edges*8
    int2*  edges2 = (int2*)w;    w += (size_t)n_edges * 8;
    float* bufB   = (float*)w;   w += (size_t)NELEM * 4;
    int* counts   = (int*)w;     w += (size_t)NBKT * 4;
    int* bkt_offs = (int*)w;     w += (size_t)(NBKT + 1) * 4;
    int* cursor   = (int*)w;     w += (size_t)NBKT * 4;
    int* row_offs = (int*)w;     // NROWS_PAD ints (row_offs[150018] lands inside)

    const int chunk = (n_edges + SC_BLOCKS - 1) / SC_BLOCKS;

    hipMemsetAsync(counts, 0, (size_t)NBKT * 4, stream);
    hist_bucket_k<<<SC_BLOCKS, SC_THREADS, 0, stream>>>(rows, counts, n_edges, chunk);
    scan_bucket_k<<<1, 1024, 0, stream>>>(counts, bkt_offs, cursor, n_edges);
    scatter_bucket_k<<<SC_BLOCKS, SC_THREADS, 0, stream>>>(rows, cols, vals, cursor,
                                                           edges1, n_edges, chunk);
    sort_bucket_k<<<NBKT, 256, 0, stream>>>(edges1, bkt_offs, edges2, row_offs);

    const int sp_grid = (N_NODES + 3) / 4;   // 4 rows (waves) per block
    // L1: x=emb -> r1 ; bufA=r1 ; out = emb + r1
    spmm_row_k<<<sp_grid, 256, 0, stream>>>((const float4*)emb, edges2, row_offs,
                                            (const float4*)emb, (float4*)bufA,
                                            (float4*)out, 1.0f, N_NODES);
    // L2: x=bufA -> r2 ; bufB=r2 ; out += r2
    spmm_row_k<<<sp_grid, 256, 0, stream>>>((const float4*)bufA, edges2, row_offs,
                                            (const float4*)out, (float4*)bufB,
                                            (float4*)out, 1.0f, N_NODES);
    // L3: x=bufB -> r3 ; out = (out + r3) * 0.25
    spmm_row_k<<<sp_grid, 256, 0, stream>>>((const float4*)bufB, edges2, row_offs,
                                            (const float4*)out, nullptr,
                                            (float4*)out, 0.25f, N_NODES);
}

// Round 5
// 713.457 us; speedup vs baseline: 7.3644x; 1.0328x over previous
//
#include <hip/hip_runtime.h>

#define N_NODES 150018
#define DIMS 64
#define NELEM (N_NODES * DIMS)            // 9,601,152 floats
#define NBKT ((N_NODES + 63) >> 6)        // 2345 buckets of 64 rows
#define NROWS_PAD (NBKT << 6)             // 150080
#define SC_BLOCKS 512
#define SC_THREADS 256

// ---- bucket histogram: LDS-privatized, coalesced global merge -----------
__global__ void hist_bucket_k(const int* __restrict__ rows, int* __restrict__ counts,
                              int n, int chunk) {
    __shared__ int h[NBKT];
    for (int i = threadIdx.x; i < NBKT; i += blockDim.x) h[i] = 0;
    __syncthreads();
    int beg = blockIdx.x * chunk;
    int end = min(n, beg + chunk);
    for (int e = beg + threadIdx.x; e < end; e += blockDim.x)
        atomicAdd(&h[rows[e] >> 6], 1);
    __syncthreads();
    for (int i = threadIdx.x; i < NBKT; i += blockDim.x)
        if (h[i]) atomicAdd(&counts[i], h[i]);
}

// ---- exclusive scan of bucket counts (single block) ---------------------
__global__ void scan_bucket_k(const int* __restrict__ counts, int* __restrict__ offs,
                              int* __restrict__ cursor, int n_edges) {
    __shared__ int s[1024];
    __shared__ int carry;
    if (threadIdx.x == 0) carry = 0;
    __syncthreads();
    for (int t = 0; t < NBKT; t += 1024) {
        int i = t + threadIdx.x;
        int v = (i < NBKT) ? counts[i] : 0;
        s[threadIdx.x] = v;
        __syncthreads();
        for (int off = 1; off < 1024; off <<= 1) {
            int tv = (threadIdx.x >= off) ? s[threadIdx.x - off] : 0;
            __syncthreads();
            s[threadIdx.x] += tv;
            __syncthreads();
        }
        if (i < NBKT) {
            int ex = carry + s[threadIdx.x] - v;
            offs[i] = ex;
            cursor[i] = ex;
        }
        __syncthreads();
        if (threadIdx.x == 1023) carry += s[1023];
        __syncthreads();
    }
    if (threadIdx.x == 0) offs[NBKT] = n_edges;
}

// ---- two-pass per-block bucket scatter (contiguous runs per block) ------
__global__ void scatter_bucket_k(const int* __restrict__ rows, const int* __restrict__ cols,
                                 const float* __restrict__ vals, int* __restrict__ cursor,
                                 int2* __restrict__ edges1, int n, int chunk) {
    __shared__ int cnt[NBKT];
    __shared__ int base[NBKT];
    for (int i = threadIdx.x; i < NBKT; i += blockDim.x) cnt[i] = 0;
    __syncthreads();
    int beg = blockIdx.x * chunk;
    int end = min(n, beg + chunk);
    for (int e = beg + threadIdx.x; e < end; e += blockDim.x)
        atomicAdd(&cnt[rows[e] >> 6], 1);
    __syncthreads();
    for (int i = threadIdx.x; i < NBKT; i += blockDim.x) {
        int c = cnt[i];
        base[i] = c ? atomicAdd(&cursor[i], c) : 0;
        cnt[i] = 0;   // reuse as running rank
    }
    __syncthreads();
    for (int e = beg + threadIdx.x; e < end; e += blockDim.x) {
        int r = rows[e];
        int b = r >> 6;
        int pos = base[b] + atomicAdd(&cnt[b], 1);
        edges1[pos] = make_int2(cols[e] | ((r & 63) << 18), __float_as_int(vals[e]));
    }
}

// ---- per-bucket 64-bin counting sort -> row-sorted edges + row offsets --
__global__ __launch_bounds__(256) void sort_bucket_k(const int2* __restrict__ e1,
                                 const int* __restrict__ bkt_offs,
                                 int2* __restrict__ e2,
                                 int* __restrict__ row_offs) {
    __shared__ int cnt[64];
    __shared__ int pref[64];
    int b = blockIdx.x;
    int beg = bkt_offs[b], end = bkt_offs[b + 1];
    if (threadIdx.x < 64) cnt[threadIdx.x] = 0;
    __syncthreads();
    for (int e = beg + threadIdx.x; e < end; e += 256)
        atomicAdd(&cnt[e1[e].x >> 18], 1);
    __syncthreads();
    if (threadIdx.x == 0) {
        int s = 0;
        for (int i = 0; i < 64; ++i) { pref[i] = s; s += cnt[i]; }
    }
    __syncthreads();
    if (threadIdx.x < 64) {
        row_offs[(b << 6) + threadIdx.x] = beg + pref[threadIdx.x];
        cnt[threadIdx.x] = 0;   // reuse as rank
    }
    __syncthreads();
    for (int e = beg + threadIdx.x; e < end; e += 256) {
        int2 ed = e1[e];
        int slot = ed.x >> 18;
        int pos = beg + pref[slot] + atomicAdd(&cnt[slot], 1);
        e2[pos] = make_int2(ed.x & 0x3FFFF, ed.y);
    }
}

// ---- SpMM: wave per row, 8 edges in flight (4 groups x unroll 2) --------
// r = A[row]·x ; buf_out=r (if non-null) ; acc_out = (acc_in + r)*scale
__global__ __launch_bounds__(256) void spmm_row_k(const float4* __restrict__ x4,
                          const int2* __restrict__ edges,
                          const int* __restrict__ offs,
                          const float4* __restrict__ acc_in,
                          float4* __restrict__ buf_out,
                          float4* __restrict__ acc_out,
                          float scale, int n_rows) {
    int row = (blockIdx.x * blockDim.x + threadIdx.x) >> 6;
    if (row >= n_rows) return;
    int lane = threadIdx.x & 63;
    int g = lane >> 4;          // edge subgroup 0..3
    int q = lane & 15;          // float4 index within row
    int o = (row << 4) + q;

    // hoist epilogue load: hide its latency under the edge loop
    float4 ai = make_float4(0.f, 0.f, 0.f, 0.f);
    if (g == 1) ai = acc_in[o];

    int beg = offs[row], end = offs[row + 1];
    float4 a0 = make_float4(0.f, 0.f, 0.f, 0.f);
    float4 a1 = make_float4(0.f, 0.f, 0.f, 0.f);
    for (int e = beg; e < end; e += 8) {
        int i0 = e + g, i1 = e + g + 4;
        int c0 = 0, c1 = 0;
        float v0 = 0.f, v1 = 0.f;
        if (i0 < end) { int2 ed = edges[i0]; c0 = ed.x; v0 = __int_as_float(ed.y); }
        if (i1 < end) { int2 ed = edges[i1]; c1 = ed.x; v1 = __int_as_float(ed.y); }
        float4 x0 = x4[(c0 << 4) + q];
        float4 x1 = x4[(c1 << 4) + q];
        a0.x = fmaf(v0, x0.x, a0.x);  a0.y = fmaf(v0, x0.y, a0.y);
        a0.z = fmaf(v0, x0.z, a0.z);  a0.w = fmaf(v0, x0.w, a0.w);
        a1.x = fmaf(v1, x1.x, a1.x);  a1.y = fmaf(v1, x1.y, a1.y);
        a1.z = fmaf(v1, x1.z, a1.z);  a1.w = fmaf(v1, x1.w, a1.w);
    }
    float4 a = make_float4(a0.x + a1.x, a0.y + a1.y, a0.z + a1.z, a0.w + a1.w);

    // reduce across the 4 subgroups (lane bits 4 and 5)
    #pragma unroll
    for (int m = 16; m <= 32; m <<= 1) {
        a.x += __shfl_xor(a.x, m, 64);
        a.y += __shfl_xor(a.y, m, 64);
        a.z += __shfl_xor(a.z, m, 64);
        a.w += __shfl_xor(a.w, m, 64);
    }
    if (g == 0 && buf_out) buf_out[o] = a;
    if (g == 1) {
        ai.x = (ai.x + a.x) * scale;
        ai.y = (ai.y + a.y) * scale;
        ai.z = (ai.z + a.z) * scale;
        ai.w = (ai.w + a.w) * scale;
        acc_out[o] = ai;
    }
}

// ---- launch -------------------------------------------------------------
extern "C" void kernel_launch(void* const* d_in, const int* in_sizes, int n_in,
                              void* d_out, int out_size, void* d_ws, size_t ws_size,
                              hipStream_t stream) {
    const float* emb  = (const float*)d_in[0];
    const float* vals = (const float*)d_in[1];
    const int*   rows = (const int*)d_in[2];
    const int*   cols = (const int*)d_in[3];
    float*       out  = (float*)d_out;
    const int n_edges = in_sizes[1];

    // workspace: region1 is edges1 during build, bufA during SpMMs
    char* w = (char*)d_ws;
    int2*  edges1 = (int2*)w;
    float* bufA   = (float*)w;   w += (size_t)NELEM * 4;     // >= n_edges*8
    int2*  edges2 = (int2*)w;    w += (size_t)n_edges * 8;
    float* bufB   = (float*)w;   w += (size_t)NELEM * 4;
    int* counts   = (int*)w;     w += (size_t)NBKT * 4;
    int* bkt_offs = (int*)w;     w += (size_t)(NBKT + 1) * 4;
    int* cursor   = (int*)w;     w += (size_t)NBKT * 4;
    int* row_offs = (int*)w;     // NROWS_PAD ints

    const int chunk = (n_edges + SC_BLOCKS - 1) / SC_BLOCKS;

    hipMemsetAsync(counts, 0, (size_t)NBKT * 4, stream);
    hist_bucket_k<<<SC_BLOCKS, SC_THREADS, 0, stream>>>(rows, counts, n_edges, chunk);
    scan_bucket_k<<<1, 1024, 0, stream>>>(counts, bkt_offs, cursor, n_edges);
    scatter_bucket_k<<<SC_BLOCKS, SC_THREADS, 0, stream>>>(rows, cols, vals, cursor,
                                                           edges1, n_edges, chunk);
    sort_bucket_k<<<NBKT, 256, 0, stream>>>(edges1, bkt_offs, edges2, row_offs);

    const int sp_grid = (N_NODES + 3) / 4;   // 4 rows (waves) per block
    // L1: x=emb -> r1 ; bufA=r1 ; out = emb + r1
    spmm_row_k<<<sp_grid, 256, 0, stream>>>((const float4*)emb, edges2, row_offs,
                                            (const float4*)emb, (float4*)bufA,
                                            (float4*)out, 1.0f, N_NODES);
    // L2: x=bufA -> r2 ; bufB=r2 ; out += r2
    spmm_row_k<<<sp_grid, 256, 0, stream>>>((const float4*)bufA, edges2, row_offs,
                                            (const float4*)out, (float4*)bufB,
                                            (float4*)out, 1.0f, N_NODES);
    // L3: x=bufB -> r3 ; out = (out + r3) * 0.25
    spmm_row_k<<<sp_grid, 256, 0, stream>>>((const float4*)bufB, edges2, row_offs,
                                            (const float4*)out, nullptr,
                                            (float4*)out, 0.25f, N_NODES);
}

// Round 6
// 543.358 us; speedup vs baseline: 9.6698x; 1.3131x over previous
//
#include <hip/hip_runtime.h>

#define N_NODES 150018
#define DIMS 64
#define NELEM (N_NODES * DIMS)            // 9,601,152 floats
#define NVEC4 (NELEM / 4)
#define NBKT ((N_NODES + 63) >> 6)        // 2345 buckets of 64 rows
#define NROWS_PAD (NBKT << 6)             // 150080
#define SC_BLOCKS 512
#define SC_THREADS 256

// ---- bf16 helpers (RNE) -------------------------------------------------
__device__ __forceinline__ unsigned short f2bf(float f) {
    unsigned int u = __float_as_uint(f);
    u += 0x7FFFu + ((u >> 16) & 1u);
    return (unsigned short)(u >> 16);
}
__device__ __forceinline__ float bf2f(unsigned short h) {
    return __uint_as_float(((unsigned int)h) << 16);
}

// ---- fp32 -> bf16 convert (vectorized) ----------------------------------
__global__ void conv_bf16_k(const float4* __restrict__ src, ushort4* __restrict__ dst, int n4) {
    int i = blockIdx.x * blockDim.x + threadIdx.x;
    if (i < n4) {
        float4 v = src[i];
        dst[i] = make_ushort4(f2bf(v.x), f2bf(v.y), f2bf(v.z), f2bf(v.w));
    }
}

// ---- bucket histogram: LDS-privatized, coalesced global merge -----------
__global__ void hist_bucket_k(const int* __restrict__ rows, int* __restrict__ counts,
                              int n, int chunk) {
    __shared__ int h[NBKT];
    for (int i = threadIdx.x; i < NBKT; i += blockDim.x) h[i] = 0;
    __syncthreads();
    int beg = blockIdx.x * chunk;
    int end = min(n, beg + chunk);
    for (int e = beg + threadIdx.x; e < end; e += blockDim.x)
        atomicAdd(&h[rows[e] >> 6], 1);
    __syncthreads();
    for (int i = threadIdx.x; i < NBKT; i += blockDim.x)
        if (h[i]) atomicAdd(&counts[i], h[i]);
}

// ---- exclusive scan of bucket counts (single block) ---------------------
__global__ void scan_bucket_k(const int* __restrict__ counts, int* __restrict__ offs,
                              int* __restrict__ cursor, int n_edges) {
    __shared__ int s[1024];
    __shared__ int carry;
    if (threadIdx.x == 0) carry = 0;
    __syncthreads();
    for (int t = 0; t < NBKT; t += 1024) {
        int i = t + threadIdx.x;
        int v = (i < NBKT) ? counts[i] : 0;
        s[threadIdx.x] = v;
        __syncthreads();
        for (int off = 1; off < 1024; off <<= 1) {
            int tv = (threadIdx.x >= off) ? s[threadIdx.x - off] : 0;
            __syncthreads();
            s[threadIdx.x] += tv;
            __syncthreads();
        }
        if (i < NBKT) {
            int ex = carry + s[threadIdx.x] - v;
            offs[i] = ex;
            cursor[i] = ex;
        }
        __syncthreads();
        if (threadIdx.x == 1023) carry += s[1023];
        __syncthreads();
    }
    if (threadIdx.x == 0) offs[NBKT] = n_edges;
}

// ---- two-pass per-block bucket scatter (contiguous runs per block) ------
__global__ void scatter_bucket_k(const int* __restrict__ rows, const int* __restrict__ cols,
                                 const float* __restrict__ vals, int* __restrict__ cursor,
                                 int2* __restrict__ edges1, int n, int chunk) {
    __shared__ int cnt[NBKT];
    __shared__ int base[NBKT];
    for (int i = threadIdx.x; i < NBKT; i += blockDim.x) cnt[i] = 0;
    __syncthreads();
    int beg = blockIdx.x * chunk;
    int end = min(n, beg + chunk);
    for (int e = beg + threadIdx.x; e < end; e += blockDim.x)
        atomicAdd(&cnt[rows[e] >> 6], 1);
    __syncthreads();
    for (int i = threadIdx.x; i < NBKT; i += blockDim.x) {
        int c = cnt[i];
        base[i] = c ? atomicAdd(&cursor[i], c) : 0;
        cnt[i] = 0;   // reuse as running rank
    }
    __syncthreads();
    for (int e = beg + threadIdx.x; e < end; e += blockDim.x) {
        int r = rows[e];
        int b = r >> 6;
        int pos = base[b] + atomicAdd(&cnt[b], 1);
        edges1[pos] = make_int2(cols[e] | ((r & 63) << 18), __float_as_int(vals[e]));
    }
}

// ---- per-bucket 64-bin counting sort -> row-sorted edges + row offsets --
__global__ __launch_bounds__(256) void sort_bucket_k(const int2* __restrict__ e1,
                                 const int* __restrict__ bkt_offs,
                                 int2* __restrict__ e2,
                                 int* __restrict__ row_offs) {
    __shared__ int cnt[64];
    __shared__ int pref[64];
    int b = blockIdx.x;
    int beg = bkt_offs[b], end = bkt_offs[b + 1];
    if (threadIdx.x < 64) cnt[threadIdx.x] = 0;
    __syncthreads();
    for (int e = beg + threadIdx.x; e < end; e += 256)
        atomicAdd(&cnt[e1[e].x >> 18], 1);
    __syncthreads();
    if (threadIdx.x == 0) {
        int s = 0;
        for (int i = 0; i < 64; ++i) { pref[i] = s; s += cnt[i]; }
    }
    __syncthreads();
    if (threadIdx.x < 64) {
        row_offs[(b << 6) + threadIdx.x] = beg + pref[threadIdx.x];
        cnt[threadIdx.x] = 0;   // reuse as rank
    }
    __syncthreads();
    for (int e = beg + threadIdx.x; e < end; e += 256) {
        int2 ed = e1[e];
        int slot = ed.x >> 18;
        int pos = beg + pref[slot] + atomicAdd(&cnt[slot], 1);
        e2[pos] = make_int2(ed.x & 0x3FFFF, ed.y);
    }
}

// ---- SpMM: wave per row, bf16 gathers, 8 edges in flight ----------------
// r = A[row]·xb ; buf_out(bf16)=r (if non-null) ; acc_out = (acc_in + r)*scale
__global__ __launch_bounds__(256) void spmm_row_k(const ushort4* __restrict__ xb,
                          const int2* __restrict__ edges,
                          const int* __restrict__ offs,
                          const float4* __restrict__ acc_in,
                          ushort4* __restrict__ buf_out,
                          float4* __restrict__ acc_out,
                          float scale, int n_rows) {
    int row = (blockIdx.x * blockDim.x + threadIdx.x) >> 6;
    if (row >= n_rows) return;
    int lane = threadIdx.x & 63;
    int g = lane >> 4;          // edge subgroup 0..3
    int q = lane & 15;          // bf16x4 index within row
    int o = (row << 4) + q;

    // hoist epilogue load: hide its latency under the edge loop
    float4 ai = make_float4(0.f, 0.f, 0.f, 0.f);
    if (g == 1) ai = acc_in[o];

    int beg = offs[row], end = offs[row + 1];
    float4 a0 = make_float4(0.f, 0.f, 0.f, 0.f);
    float4 a1 = make_float4(0.f, 0.f, 0.f, 0.f);
    for (int e = beg; e < end; e += 8) {
        int i0 = e + g, i1 = e + g + 4;
        int c0 = 0, c1 = 0;
        float v0 = 0.f, v1 = 0.f;
        if (i0 < end) { int2 ed = edges[i0]; c0 = ed.x; v0 = __int_as_float(ed.y); }
        if (i1 < end) { int2 ed = edges[i1]; c1 = ed.x; v1 = __int_as_float(ed.y); }
        ushort4 x0 = xb[(c0 << 4) + q];
        ushort4 x1 = xb[(c1 << 4) + q];
        a0.x = fmaf(v0, bf2f(x0.x), a0.x);  a0.y = fmaf(v0, bf2f(x0.y), a0.y);
        a0.z = fmaf(v0, bf2f(x0.z), a0.z);  a0.w = fmaf(v0, bf2f(x0.w), a0.w);
        a1.x = fmaf(v1, bf2f(x1.x), a1.x);  a1.y = fmaf(v1, bf2f(x1.y), a1.y);
        a1.z = fmaf(v1, bf2f(x1.z), a1.z);  a1.w = fmaf(v1, bf2f(x1.w), a1.w);
    }
    float4 a = make_float4(a0.x + a1.x, a0.y + a1.y, a0.z + a1.z, a0.w + a1.w);

    // reduce across the 4 subgroups (lane bits 4 and 5)
    #pragma unroll
    for (int m = 16; m <= 32; m <<= 1) {
        a.x += __shfl_xor(a.x, m, 64);
        a.y += __shfl_xor(a.y, m, 64);
        a.z += __shfl_xor(a.z, m, 64);
        a.w += __shfl_xor(a.w, m, 64);
    }
    if (g == 0 && buf_out)
        buf_out[o] = make_ushort4(f2bf(a.x), f2bf(a.y), f2bf(a.z), f2bf(a.w));
    if (g == 1) {
        ai.x = (ai.x + a.x) * scale;
        ai.y = (ai.y + a.y) * scale;
        ai.z = (ai.z + a.z) * scale;
        ai.w = (ai.w + a.w) * scale;
        acc_out[o] = ai;
    }
}

// ---- launch -------------------------------------------------------------
extern "C" void kernel_launch(void* const* d_in, const int* in_sizes, int n_in,
                              void* d_out, int out_size, void* d_ws, size_t ws_size,
                              hipStream_t stream) {
    const float* emb  = (const float*)d_in[0];
    const float* vals = (const float*)d_in[1];
    const int*   rows = (const int*)d_in[2];
    const int*   cols = (const int*)d_in[3];
    float*       out  = (float*)d_out;
    const int n_edges = in_sizes[1];

    // workspace: region1 holds edges1 during build, then bufAb+bufBb (bf16)
    char* w = (char*)d_ws;
    int2*   edges1 = (int2*)w;
    ushort* bufAb  = (ushort*)w;
    ushort* bufBb  = (ushort*)(w + (size_t)NELEM * 2);
    w += (size_t)NELEM * 4;                       // covers max(edges1, bufAb+bufBb)
    int2*   edges2 = (int2*)w;   w += (size_t)n_edges * 8;
    ushort* embb   = (ushort*)w; w += (size_t)NELEM * 2;
    int* counts    = (int*)w;    w += (size_t)NBKT * 4;
    int* bkt_offs  = (int*)w;    w += (size_t)(NBKT + 1) * 4;
    int* cursor    = (int*)w;    w += (size_t)NBKT * 4;
    int* row_offs  = (int*)w;    // NROWS_PAD ints

    const int chunk = (n_edges + SC_BLOCKS - 1) / SC_BLOCKS;

    hipMemsetAsync(counts, 0, (size_t)NBKT * 4, stream);
    hist_bucket_k<<<SC_BLOCKS, SC_THREADS, 0, stream>>>(rows, counts, n_edges, chunk);
    scan_bucket_k<<<1, 1024, 0, stream>>>(counts, bkt_offs, cursor, n_edges);
    scatter_bucket_k<<<SC_BLOCKS, SC_THREADS, 0, stream>>>(rows, cols, vals, cursor,
                                                           edges1, n_edges, chunk);
    sort_bucket_k<<<NBKT, 256, 0, stream>>>(edges1, bkt_offs, edges2, row_offs);
    conv_bf16_k<<<(NVEC4 + 255) / 256, 256, 0, stream>>>((const float4*)emb,
                                                         (ushort4*)embb, NVEC4);

    const int sp_grid = (N_NODES + 3) / 4;   // 4 rows (waves) per block
    // L1: x=embb -> r1 ; bufAb=bf16(r1) ; out = emb + r1
    spmm_row_k<<<sp_grid, 256, 0, stream>>>((const ushort4*)embb, edges2, row_offs,
                                            (const float4*)emb, (ushort4*)bufAb,
                                            (float4*)out, 1.0f, N_NODES);
    // L2: x=bufAb -> r2 ; bufBb=bf16(r2) ; out += r2
    spmm_row_k<<<sp_grid, 256, 0, stream>>>((const ushort4*)bufAb, edges2, row_offs,
                                            (const float4*)out, (ushort4*)bufBb,
                                            (float4*)out, 1.0f, N_NODES);
    // L3: x=bufBb -> r3 ; out = (out + r3) * 0.25
    spmm_row_k<<<sp_grid, 256, 0, stream>>>((const ushort4*)bufBb, edges2, row_offs,
                                            (const float4*)out, nullptr,
                                            (float4*)out, 0.25f, N_NODES);
}

// Round 7
// 520.872 us; speedup vs baseline: 10.0872x; 1.0432x over previous
//
#include <hip/hip_runtime.h>

#define N_NODES 150018
#define DIMS 64
#define NELEM (N_NODES * DIMS)            // 9,601,152 floats
#define NVEC4 (NELEM / 4)
#define NBKT ((N_NODES + 255) >> 8)       // 587 buckets of 256 rows
#define SC_BLOCKS 512
#define SC_THREADS 1024

// ---- bf16 helpers (RNE) -------------------------------------------------
__device__ __forceinline__ unsigned short f2bf(float f) {
    unsigned int u = __float_as_uint(f);
    u += 0x7FFFu + ((u >> 16) & 1u);
    return (unsigned short)(u >> 16);
}
__device__ __forceinline__ float bf2f(unsigned short h) {
    return __uint_as_float(((unsigned int)h) << 16);
}

// ---- fp32 -> bf16 convert (vectorized) ----------------------------------
__global__ void conv_bf16_k(const float4* __restrict__ src, ushort4* __restrict__ dst, int n4) {
    int i = blockIdx.x * blockDim.x + threadIdx.x;
    if (i < n4) {
        float4 v = src[i];
        dst[i] = make_ushort4(f2bf(v.x), f2bf(v.y), f2bf(v.z), f2bf(v.w));
    }
}

// ---- bucket histogram: LDS-privatized, coalesced global merge -----------
__global__ __launch_bounds__(SC_THREADS) void hist_bucket_k(const int* __restrict__ rows,
                              int* __restrict__ counts, int n, int chunk) {
    __shared__ int h[NBKT];
    for (int i = threadIdx.x; i < NBKT; i += blockDim.x) h[i] = 0;
    __syncthreads();
    int beg = blockIdx.x * chunk;
    int end = min(n, beg + chunk);
    for (int e = beg + threadIdx.x; e < end; e += blockDim.x)
        atomicAdd(&h[rows[e] >> 8], 1);
    __syncthreads();
    for (int i = threadIdx.x; i < NBKT; i += blockDim.x)
        if (h[i]) atomicAdd(&counts[i], h[i]);
}

// ---- exclusive scan of bucket counts (single block) ---------------------
__global__ void scan_bucket_k(const int* __restrict__ counts, int* __restrict__ offs,
                              int* __restrict__ cursor, int n_edges) {
    __shared__ int s[1024];
    __shared__ int carry;
    if (threadIdx.x == 0) carry = 0;
    __syncthreads();
    for (int t = 0; t < NBKT; t += 1024) {
        int i = t + threadIdx.x;
        int v = (i < NBKT) ? counts[i] : 0;
        s[threadIdx.x] = v;
        __syncthreads();
        for (int off = 1; off < 1024; off <<= 1) {
            int tv = (threadIdx.x >= off) ? s[threadIdx.x - off] : 0;
            __syncthreads();
            s[threadIdx.x] += tv;
            __syncthreads();
        }
        if (i < NBKT) {
            int ex = carry + s[threadIdx.x] - v;
            offs[i] = ex;
            cursor[i] = ex;
        }
        __syncthreads();
        if (threadIdx.x == 1023) carry += s[1023];
        __syncthreads();
    }
    if (threadIdx.x == 0) offs[NBKT] = n_edges;
}

// ---- two-pass per-block bucket scatter (contiguous runs per block) ------
// edges1[pos] = (col | slot<<18, val_bits), slot = row & 255
__global__ __launch_bounds__(SC_THREADS) void scatter_bucket_k(const int* __restrict__ rows,
                                 const int* __restrict__ cols,
                                 const float* __restrict__ vals, int* __restrict__ cursor,
                                 int2* __restrict__ edges1, int n, int chunk) {
    __shared__ int cnt[NBKT];
    __shared__ int base[NBKT];
    for (int i = threadIdx.x; i < NBKT; i += blockDim.x) cnt[i] = 0;
    __syncthreads();
    int beg = blockIdx.x * chunk;
    int end = min(n, beg + chunk);
    for (int e = beg + threadIdx.x; e < end; e += blockDim.x)
        atomicAdd(&cnt[rows[e] >> 8], 1);
    __syncthreads();
    for (int i = threadIdx.x; i < NBKT; i += blockDim.x) {
        int c = cnt[i];
        base[i] = c ? atomicAdd(&cursor[i], c) : 0;
        cnt[i] = 0;   // reuse as running rank
    }
    __syncthreads();
    for (int e = beg + threadIdx.x; e < end; e += blockDim.x) {
        int r = rows[e];
        int b = r >> 8;
        int pos = base[b] + atomicAdd(&cnt[b], 1);
        edges1[pos] = make_int2(cols[e] | ((r & 255) << 18), __float_as_int(vals[e]));
    }
}

// ---- per-bucket 256-bin counting sort -> row-sorted edges + row offsets --
__global__ __launch_bounds__(512) void sort_bucket_k(const int2* __restrict__ e1,
                                 const int* __restrict__ bkt_offs,
                                 int2* __restrict__ e2,
                                 int* __restrict__ row_offs) {
    __shared__ int cnt[256];
    __shared__ int pref[256];
    int b = blockIdx.x;
    int beg = bkt_offs[b], end = bkt_offs[b + 1];
    if (threadIdx.x < 256) cnt[threadIdx.x] = 0;
    __syncthreads();
    for (int e = beg + threadIdx.x; e < end; e += 512)
        atomicAdd(&cnt[e1[e].x >> 18], 1);
    __syncthreads();
    // Hillis-Steele inclusive scan over 256 bins
    int v = 0;
    if (threadIdx.x < 256) { v = cnt[threadIdx.x]; pref[threadIdx.x] = v; }
    __syncthreads();
    for (int off = 1; off < 256; off <<= 1) {
        int t = (threadIdx.x >= off && threadIdx.x < 256) ? pref[threadIdx.x - off] : 0;
        __syncthreads();
        if (threadIdx.x < 256) pref[threadIdx.x] += t;
        __syncthreads();
    }
    if (threadIdx.x < 256) {
        int ex = pref[threadIdx.x] - v;
        row_offs[(b << 8) + threadIdx.x] = beg + ex;
        pref[threadIdx.x] = ex;      // own-slot overwrite, no cross-read here
        cnt[threadIdx.x] = 0;        // reuse as rank
    }
    __syncthreads();
    for (int e = beg + threadIdx.x; e < end; e += 512) {
        int2 ed = e1[e];
        int slot = ed.x >> 18;
        int pos = beg + pref[slot] + atomicAdd(&cnt[slot], 1);
        e2[pos] = make_int2(ed.x & 0x3FFFF, ed.y);
    }
}

// ---- SpMM: wave per row, bf16 gathers, 8 edges in flight ----------------
// r = A[row]·xb ; buf_out(bf16)=r (if non-null) ; acc_out = (acc_in + r)*scale
__global__ __launch_bounds__(256) void spmm_row_k(const ushort4* __restrict__ xb,
                          const int2* __restrict__ edges,
                          const int* __restrict__ offs,
                          const float4* __restrict__ acc_in,
                          ushort4* __restrict__ buf_out,
                          float4* __restrict__ acc_out,
                          float scale, int n_rows) {
    int row = (blockIdx.x * blockDim.x + threadIdx.x) >> 6;
    if (row >= n_rows) return;
    int lane = threadIdx.x & 63;
    int g = lane >> 4;          // edge subgroup 0..3
    int q = lane & 15;          // bf16x4 index within row
    int o = (row << 4) + q;

    float4 ai = make_float4(0.f, 0.f, 0.f, 0.f);
    if (g == 1) ai = acc_in[o];

    int beg = offs[row], end = offs[row + 1];
    float4 a0 = make_float4(0.f, 0.f, 0.f, 0.f);
    float4 a1 = make_float4(0.f, 0.f, 0.f, 0.f);
    for (int e = beg; e < end; e += 8) {
        int i0 = e + g, i1 = e + g + 4;
        int c0 = 0, c1 = 0;
        float v0 = 0.f, v1 = 0.f;
        if (i0 < end) { int2 ed = edges[i0]; c0 = ed.x; v0 = __int_as_float(ed.y); }
        if (i1 < end) { int2 ed = edges[i1]; c1 = ed.x; v1 = __int_as_float(ed.y); }
        ushort4 x0 = xb[(c0 << 4) + q];
        ushort4 x1 = xb[(c1 << 4) + q];
        a0.x = fmaf(v0, bf2f(x0.x), a0.x);  a0.y = fmaf(v0, bf2f(x0.y), a0.y);
        a0.z = fmaf(v0, bf2f(x0.z), a0.z);  a0.w = fmaf(v0, bf2f(x0.w), a0.w);
        a1.x = fmaf(v1, bf2f(x1.x), a1.x);  a1.y = fmaf(v1, bf2f(x1.y), a1.y);
        a1.z = fmaf(v1, bf2f(x1.z), a1.z);  a1.w = fmaf(v1, bf2f(x1.w), a1.w);
    }
    float4 a = make_float4(a0.x + a1.x, a0.y + a1.y, a0.z + a1.z, a0.w + a1.w);

    #pragma unroll
    for (int m = 16; m <= 32; m <<= 1) {
        a.x += __shfl_xor(a.x, m, 64);
        a.y += __shfl_xor(a.y, m, 64);
        a.z += __shfl_xor(a.z, m, 64);
        a.w += __shfl_xor(a.w, m, 64);
    }
    if (g == 0 && buf_out)
        buf_out[o] = make_ushort4(f2bf(a.x), f2bf(a.y), f2bf(a.z), f2bf(a.w));
    if (g == 1) {
        ai.x = (ai.x + a.x) * scale;
        ai.y = (ai.y + a.y) * scale;
        ai.z = (ai.z + a.z) * scale;
        ai.w = (ai.w + a.w) * scale;
        acc_out[o] = ai;
    }
}

// ---- launch -------------------------------------------------------------
extern "C" void kernel_launch(void* const* d_in, const int* in_sizes, int n_in,
                              void* d_out, int out_size, void* d_ws, size_t ws_size,
                              hipStream_t stream) {
    const float* emb  = (const float*)d_in[0];
    const float* vals = (const float*)d_in[1];
    const int*   rows = (const int*)d_in[2];
    const int*   cols = (const int*)d_in[3];
    float*       out  = (float*)d_out;
    const int n_edges = in_sizes[1];

    // workspace: region1 holds edges1 during build, then bufAb+bufBb (bf16)
    char* w = (char*)d_ws;
    int2*   edges1 = (int2*)w;
    ushort* bufAb  = (ushort*)w;
    ushort* bufBb  = (ushort*)(w + (size_t)NELEM * 2);
    w += (size_t)NELEM * 4;                       // covers max(edges1, bufAb+bufBb)
    int2*   edges2 = (int2*)w;   w += (size_t)n_edges * 8;
    ushort* embb   = (ushort*)w; w += (size_t)NELEM * 2;
    int* counts    = (int*)w;    w += (size_t)NBKT * 4;
    int* bkt_offs  = (int*)w;    w += (size_t)(NBKT + 1) * 4;
    int* cursor    = (int*)w;    w += (size_t)NBKT * 4;
    int* row_offs  = (int*)w;    // (NBKT<<8) ints

    const int chunk = (n_edges + SC_BLOCKS - 1) / SC_BLOCKS;

    hipMemsetAsync(counts, 0, (size_t)NBKT * 4, stream);
    hist_bucket_k<<<SC_BLOCKS, SC_THREADS, 0, stream>>>(rows, counts, n_edges, chunk);
    scan_bucket_k<<<1, 1024, 0, stream>>>(counts, bkt_offs, cursor, n_edges);
    scatter_bucket_k<<<SC_BLOCKS, SC_THREADS, 0, stream>>>(rows, cols, vals, cursor,
                                                           edges1, n_edges, chunk);
    sort_bucket_k<<<NBKT, 512, 0, stream>>>(edges1, bkt_offs, edges2, row_offs);
    conv_bf16_k<<<(NVEC4 + 255) / 256, 256, 0, stream>>>((const float4*)emb,
                                                         (ushort4*)embb, NVEC4);

    const int sp_grid = (N_NODES + 3) / 4;   // 4 rows (waves) per block
    // L1: x=embb -> r1 ; bufAb=bf16(r1) ; out = emb + r1
    spmm_row_k<<<sp_grid, 256, 0, stream>>>((const ushort4*)embb, edges2, row_offs,
                                            (const float4*)emb, (ushort4*)bufAb,
                                            (float4*)out, 1.0f, N_NODES);
    // L2: x=bufAb -> r2 ; bufBb=bf16(r2) ; out += r2
    spmm_row_k<<<sp_grid, 256, 0, stream>>>((const ushort4*)bufAb, edges2, row_offs,
                                            (const float4*)out, (ushort4*)bufBb,
                                            (float4*)out, 1.0f, N_NODES);
    // L3: x=bufBb -> r3 ; out = (out + r3) * 0.25
    spmm_row_k<<<sp_grid, 256, 0, stream>>>((const ushort4*)bufBb, edges2, row_offs,
                                            (const float4*)out, nullptr,
                                            (float4*)out, 0.25f, N_NODES);
}

// Round 8
// 434.651 us; speedup vs baseline: 12.0882x; 1.1984x over previous
//
#include <hip/hip_runtime.h>

#define N_NODES 150018
#define DIMS 64
#define NELEM (N_NODES * DIMS)            // 9,601,152 floats
#define NVEC4 (NELEM / 4)
#define NBKT ((N_NODES + 255) >> 8)       // 587 buckets of 256 rows
#define PADCAP 1792                       // max pad entries per bucket (256 rows * 7)
#define SC_BLOCKS 512
#define SC_THREADS 1024

// ---- bf16 helpers (RNE) -------------------------------------------------
__device__ __forceinline__ unsigned short f2bf(float f) {
    unsigned int u = __float_as_uint(f);
    u += 0x7FFFu + ((u >> 16) & 1u);
    return (unsigned short)(u >> 16);
}
__device__ __forceinline__ float bf2f(unsigned short h) {
    return __uint_as_float(((unsigned int)h) << 16);
}

// ---- fp32 -> bf16 convert (vectorized) ----------------------------------
__global__ void conv_bf16_k(const float4* __restrict__ src, ushort4* __restrict__ dst, int n4) {
    int i = blockIdx.x * blockDim.x + threadIdx.x;
    if (i < n4) {
        float4 v = src[i];
        dst[i] = make_ushort4(f2bf(v.x), f2bf(v.y), f2bf(v.z), f2bf(v.w));
    }
}

// ---- bucket histogram: LDS-privatized, coalesced global merge -----------
__global__ __launch_bounds__(SC_THREADS) void hist_bucket_k(const int* __restrict__ rows,
                              int* __restrict__ counts, int n, int chunk) {
    __shared__ int h[NBKT];
    for (int i = threadIdx.x; i < NBKT; i += blockDim.x) h[i] = 0;
    __syncthreads();
    int beg = blockIdx.x * chunk;
    int end = min(n, beg + chunk);
    for (int e = beg + threadIdx.x; e < end; e += blockDim.x)
        atomicAdd(&h[rows[e] >> 8], 1);
    __syncthreads();
    for (int i = threadIdx.x; i < NBKT; i += blockDim.x)
        if (h[i]) atomicAdd(&counts[i], h[i]);
}

// ---- exclusive scan of bucket counts (single block) ---------------------
__global__ void scan_bucket_k(const int* __restrict__ counts, int* __restrict__ offs,
                              int* __restrict__ cursor, int n_edges) {
    __shared__ int s[1024];
    __shared__ int carry;
    if (threadIdx.x == 0) carry = 0;
    __syncthreads();
    for (int t = 0; t < NBKT; t += 1024) {
        int i = t + threadIdx.x;
        int v = (i < NBKT) ? counts[i] : 0;
        s[threadIdx.x] = v;
        __syncthreads();
        for (int off = 1; off < 1024; off <<= 1) {
            int tv = (threadIdx.x >= off) ? s[threadIdx.x - off] : 0;
            __syncthreads();
            s[threadIdx.x] += tv;
            __syncthreads();
        }
        if (i < NBKT) {
            int ex = carry + s[threadIdx.x] - v;
            offs[i] = ex;
            cursor[i] = ex;
        }
        __syncthreads();
        if (threadIdx.x == 1023) carry += s[1023];
        __syncthreads();
    }
    if (threadIdx.x == 0) offs[NBKT] = n_edges;
}

// ---- two-pass per-block bucket scatter (contiguous runs per block) ------
// edges1[pos] = (col | slot<<18, val_bits), slot = row & 255
__global__ __launch_bounds__(SC_THREADS) void scatter_bucket_k(const int* __restrict__ rows,
                                 const int* __restrict__ cols,
                                 const float* __restrict__ vals, int* __restrict__ cursor,
                                 int2* __restrict__ edges1, int n, int chunk) {
    __shared__ int cnt[NBKT];
    __shared__ int base[NBKT];
    for (int i = threadIdx.x; i < NBKT; i += blockDim.x) cnt[i] = 0;
    __syncthreads();
    int beg = blockIdx.x * chunk;
    int end = min(n, beg + chunk);
    for (int e = beg + threadIdx.x; e < end; e += blockDim.x)
        atomicAdd(&cnt[rows[e] >> 8], 1);
    __syncthreads();
    for (int i = threadIdx.x; i < NBKT; i += blockDim.x) {
        int c = cnt[i];
        base[i] = c ? atomicAdd(&cursor[i], c) : 0;
        cnt[i] = 0;   // reuse as running rank
    }
    __syncthreads();
    for (int e = beg + threadIdx.x; e < end; e += blockDim.x) {
        int r = rows[e];
        int b = r >> 8;
        int pos = base[b] + atomicAdd(&cnt[b], 1);
        edges1[pos] = make_int2(cols[e] | ((r & 255) << 18), __float_as_int(vals[e]));
    }
}

// ---- per-bucket 256-bin counting sort with pad-to-8 per row -------------
// e2 gets row-sorted edges, each row padded to multiple of 8 with (0,0).
// row_offs stride 257/bucket: [b*257+slot]=row start, [b*257+256]=bucket end.
__global__ __launch_bounds__(512) void sort_bucket_k(const int2* __restrict__ e1,
                                 const int* __restrict__ bkt_offs,
                                 int2* __restrict__ e2,
                                 int* __restrict__ row_offs) {
    __shared__ int cnt[256];
    __shared__ int pref[256];
    __shared__ int rank[256];
    int b = blockIdx.x;
    int beg = bkt_offs[b], end = bkt_offs[b + 1];
    int padbase = beg + b * PADCAP;
    if (threadIdx.x < 256) cnt[threadIdx.x] = 0;
    __syncthreads();
    for (int e = beg + threadIdx.x; e < end; e += 512)
        atomicAdd(&cnt[e1[e].x >> 18], 1);
    __syncthreads();
    // Hillis-Steele inclusive scan over padded counts
    int pc = 0;
    if (threadIdx.x < 256) {
        pc = (cnt[threadIdx.x] + 7) & ~7;
        pref[threadIdx.x] = pc;
    }
    __syncthreads();
    for (int off = 1; off < 256; off <<= 1) {
        int t = (threadIdx.x >= off && threadIdx.x < 256) ? pref[threadIdx.x - off] : 0;
        __syncthreads();
        if (threadIdx.x < 256) pref[threadIdx.x] += t;
        __syncthreads();
    }
    if (threadIdx.x < 256) {
        int ex = pref[threadIdx.x] - pc;          // padded exclusive prefix
        row_offs[b * 257 + threadIdx.x] = padbase + ex;
        if (threadIdx.x == 255) row_offs[b * 257 + 256] = padbase + pref[255];
        pref[threadIdx.x] = ex;
        rank[threadIdx.x] = 0;
        // zero-fill this row's pad region [ex+cnt, ex+pc)
        int fb = padbase + ex + cnt[threadIdx.x];
        int fe = padbase + ex + pc;
        for (int i = fb; i < fe; ++i) e2[i] = make_int2(0, 0);
    }
    __syncthreads();
    for (int e = beg + threadIdx.x; e < end; e += 512) {
        int2 ed = e1[e];
        int slot = ed.x >> 18;
        int pos = padbase + pref[slot] + atomicAdd(&rank[slot], 1);
        e2[pos] = make_int2(ed.x & 0x3FFFF, ed.y);
    }
}

// ---- mid SpMM: wave per row, padded rows (no masks), bf16 in/out --------
__global__ __launch_bounds__(256) void spmm_mid_k(const ushort4* __restrict__ xb,
                          const int2* __restrict__ edges,
                          const int* __restrict__ row_offs,
                          ushort4* __restrict__ buf_out, int n_rows) {
    int row = (blockIdx.x * blockDim.x + threadIdx.x) >> 6;
    if (row >= n_rows) return;
    int lane = threadIdx.x & 63;
    int g = lane >> 4, q = lane & 15;
    int oi = (row >> 8) * 257 + (row & 255);
    int beg = row_offs[oi], end = row_offs[oi + 1];
    float4 a0 = make_float4(0.f, 0.f, 0.f, 0.f);
    float4 a1 = make_float4(0.f, 0.f, 0.f, 0.f);
    for (int e = beg; e < end; e += 8) {
        int2 e0 = edges[e + g];
        int2 e1 = edges[e + g + 4];
        ushort4 x0 = xb[(e0.x << 4) + q];
        ushort4 x1 = xb[(e1.x << 4) + q];
        float v0 = __int_as_float(e0.y), v1 = __int_as_float(e1.y);
        a0.x = fmaf(v0, bf2f(x0.x), a0.x);  a0.y = fmaf(v0, bf2f(x0.y), a0.y);
        a0.z = fmaf(v0, bf2f(x0.z), a0.z);  a0.w = fmaf(v0, bf2f(x0.w), a0.w);
        a1.x = fmaf(v1, bf2f(x1.x), a1.x);  a1.y = fmaf(v1, bf2f(x1.y), a1.y);
        a1.z = fmaf(v1, bf2f(x1.z), a1.z);  a1.w = fmaf(v1, bf2f(x1.w), a1.w);
    }
    float4 a = make_float4(a0.x + a1.x, a0.y + a1.y, a0.z + a1.z, a0.w + a1.w);
    #pragma unroll
    for (int m = 16; m <= 32; m <<= 1) {
        a.x += __shfl_xor(a.x, m, 64);
        a.y += __shfl_xor(a.y, m, 64);
        a.z += __shfl_xor(a.z, m, 64);
        a.w += __shfl_xor(a.w, m, 64);
    }
    if (g == 0)
        buf_out[(row << 4) + q] = make_ushort4(f2bf(a.x), f2bf(a.y), f2bf(a.z), f2bf(a.w));
}

// ---- final SpMM: out = (emb + bf(r1) + bf(r2) + r3) * 0.25 --------------
__global__ __launch_bounds__(256) void spmm_final_k(const ushort4* __restrict__ xb,
                          const int2* __restrict__ edges,
                          const int* __restrict__ row_offs,
                          const float4* __restrict__ emb,
                          const ushort4* __restrict__ bufA,
                          const ushort4* __restrict__ bufB,
                          float4* __restrict__ out, int n_rows) {
    int row = (blockIdx.x * blockDim.x + threadIdx.x) >> 6;
    if (row >= n_rows) return;
    int lane = threadIdx.x & 63;
    int g = lane >> 4, q = lane & 15;
    int o = (row << 4) + q;

    // hoist epilogue loads: latency hides under edge loop
    float4 em = make_float4(0.f, 0.f, 0.f, 0.f);
    ushort4 ra = make_ushort4(0, 0, 0, 0), rb = make_ushort4(0, 0, 0, 0);
    if (g == 1) { em = emb[o]; ra = bufA[o]; rb = bufB[o]; }

    int oi = (row >> 8) * 257 + (row & 255);
    int beg = row_offs[oi], end = row_offs[oi + 1];
    float4 a0 = make_float4(0.f, 0.f, 0.f, 0.f);
    float4 a1 = make_float4(0.f, 0.f, 0.f, 0.f);
    for (int e = beg; e < end; e += 8) {
        int2 e0 = edges[e + g];
        int2 e1 = edges[e + g + 4];
        ushort4 x0 = xb[(e0.x << 4) + q];
        ushort4 x1 = xb[(e1.x << 4) + q];
        float v0 = __int_as_float(e0.y), v1 = __int_as_float(e1.y);
        a0.x = fmaf(v0, bf2f(x0.x), a0.x);  a0.y = fmaf(v0, bf2f(x0.y), a0.y);
        a0.z = fmaf(v0, bf2f(x0.z), a0.z);  a0.w = fmaf(v0, bf2f(x0.w), a0.w);
        a1.x = fmaf(v1, bf2f(x1.x), a1.x);  a1.y = fmaf(v1, bf2f(x1.y), a1.y);
        a1.z = fmaf(v1, bf2f(x1.z), a1.z);  a1.w = fmaf(v1, bf2f(x1.w), a1.w);
    }
    float4 a = make_float4(a0.x + a1.x, a0.y + a1.y, a0.z + a1.z, a0.w + a1.w);
    #pragma unroll
    for (int m = 16; m <= 32; m <<= 1) {
        a.x += __shfl_xor(a.x, m, 64);
        a.y += __shfl_xor(a.y, m, 64);
        a.z += __shfl_xor(a.z, m, 64);
        a.w += __shfl_xor(a.w, m, 64);
    }
    if (g == 1) {
        float4 r;
        r.x = (em.x + bf2f(ra.x) + bf2f(rb.x) + a.x) * 0.25f;
        r.y = (em.y + bf2f(ra.y) + bf2f(rb.y) + a.y) * 0.25f;
        r.z = (em.z + bf2f(ra.z) + bf2f(rb.z) + a.z) * 0.25f;
        r.w = (em.w + bf2f(ra.w) + bf2f(rb.w) + a.w) * 0.25f;
        out[o] = r;
    }
}

// ---- launch -------------------------------------------------------------
extern "C" void kernel_launch(void* const* d_in, const int* in_sizes, int n_in,
                              void* d_out, int out_size, void* d_ws, size_t ws_size,
                              hipStream_t stream) {
    const float* emb  = (const float*)d_in[0];
    const float* vals = (const float*)d_in[1];
    const int*   rows = (const int*)d_in[2];
    const int*   cols = (const int*)d_in[3];
    float*       out  = (float*)d_out;
    const int n_edges = in_sizes[1];

    // workspace: region1 holds edges1 during build, then bufAb+bufBb (bf16)
    char* w = (char*)d_ws;
    int2*   edges1 = (int2*)w;
    ushort* bufAb  = (ushort*)w;
    ushort* bufBb  = (ushort*)(w + (size_t)NELEM * 2);
    w += (size_t)NELEM * 4;                          // max(edges1, bufAb+bufBb)
    int2*   edges2 = (int2*)w;   w += ((size_t)n_edges + (size_t)NBKT * PADCAP) * 8;
    ushort* embb   = (ushort*)w; w += (size_t)NELEM * 2;
    int* counts    = (int*)w;    w += (size_t)NBKT * 4;
    int* bkt_offs  = (int*)w;    w += (size_t)(NBKT + 1) * 4;
    int* cursor    = (int*)w;    w += (size_t)NBKT * 4;
    int* row_offs  = (int*)w;    // NBKT*257 ints

    const int chunk = (n_edges + SC_BLOCKS - 1) / SC_BLOCKS;

    hipMemsetAsync(counts, 0, (size_t)NBKT * 4, stream);
    hist_bucket_k<<<SC_BLOCKS, SC_THREADS, 0, stream>>>(rows, counts, n_edges, chunk);
    scan_bucket_k<<<1, 1024, 0, stream>>>(counts, bkt_offs, cursor, n_edges);
    scatter_bucket_k<<<SC_BLOCKS, SC_THREADS, 0, stream>>>(rows, cols, vals, cursor,
                                                           edges1, n_edges, chunk);
    sort_bucket_k<<<NBKT, 512, 0, stream>>>(edges1, bkt_offs, edges2, row_offs);
    conv_bf16_k<<<(NVEC4 + 255) / 256, 256, 0, stream>>>((const float4*)emb,
                                                         (ushort4*)embb, NVEC4);

    const int sp_grid = (N_NODES + 3) / 4;   // 4 rows (waves) per block
    // L1: r1 = A·embb -> bufAb (bf16)
    spmm_mid_k<<<sp_grid, 256, 0, stream>>>((const ushort4*)embb, edges2, row_offs,
                                            (ushort4*)bufAb, N_NODES);
    // L2: r2 = A·bufAb -> bufBb (bf16)
    spmm_mid_k<<<sp_grid, 256, 0, stream>>>((const ushort4*)bufAb, edges2, row_offs,
                                            (ushort4*)bufBb, N_NODES);
    // L3: out = (emb + bf(r1) + bf(r2) + A·bufBb) * 0.25
    spmm_final_k<<<sp_grid, 256, 0, stream>>>((const ushort4*)bufBb, edges2, row_offs,
                                              (const float4*)emb, (const ushort4*)bufAb,
                                              (const ushort4*)bufBb, (float4*)out, N_NODES);
}